// Round 1
// baseline (1055.694 us; speedup 1.0000x reference)
//
#include <hip/hip_runtime.h>

// ImageCaptionModel: B=128 T=32 V=10000 H=512 E=512 F=2048 NM=512
// D0=1536 D1=1024. All GEMMs bf16-MFMA (16x16x32) with fp32 accum.
// This version fuses the per-step logits GEMM (H1(t) @ W_out) into the
// recurrence phase launches as extra blocks: logits(t-1) runs on CUs that
// are otherwise idle during the latency-bound LSTM step.

typedef short s8v __attribute__((ext_vector_type(8)));   // 8 x bf16 bits
typedef float f4v __attribute__((ext_vector_type(4)));   // MFMA acc

__device__ __forceinline__ unsigned short f2bf(float f) {
  unsigned u = __float_as_uint(f);
  u += 0x7fffu + ((u >> 16) & 1u);          // round-to-nearest-even
  return (unsigned short)(u >> 16);
}
__device__ __forceinline__ float sigm(float x) { return 1.0f / (1.0f + __expf(-x)); }
__device__ __forceinline__ float tanh_(float x) { return 1.0f - 2.0f / (1.0f + __expf(2.0f * x)); }

__device__ __forceinline__ void glds16(const unsigned short* g, unsigned short* l) {
  __builtin_amdgcn_global_load_lds((const __attribute__((address_space(1))) void*)g,
                                   (__attribute__((address_space(3))) void*)l, 16, 0, 0);
}

// ---- transpose + fp32->bf16: dst[c][r] = src[r][c] ----
__global__ void k_transpose_cvt(const float* __restrict__ src, unsigned short* __restrict__ dst,
                                int R, int C) {
  __shared__ float tile[32][33];
  int c0 = blockIdx.x * 32, r0 = blockIdx.y * 32;
  int tx = threadIdx.x, ty = threadIdx.y;
#pragma unroll
  for (int i = 0; i < 4; i++) {
    int r = r0 + ty + i * 8, c = c0 + tx;
    if (r < R && c < C) tile[ty + i * 8][tx] = src[(size_t)r * C + c];
  }
  __syncthreads();
#pragma unroll
  for (int i = 0; i < 4; i++) {
    int c = c0 + ty + i * 8, r = r0 + tx;
    if (r < R && c < C) dst[(size_t)c * R + r] = f2bf(tile[tx][ty + i * 8]);
  }
}

// ---- fp32 -> bf16 (vec4) ----
__global__ void k_cvt_bf16(const float* __restrict__ in, unsigned short* __restrict__ out, int n4) {
  int i = blockIdx.x * 256 + threadIdx.x;
  if (i >= n4) return;
  float4 v = ((const float4*)in)[i];
  ushort4 p; p.x = f2bf(v.x); p.y = f2bf(v.y); p.z = f2bf(v.z); p.w = f2bf(v.w);
  ((ushort4*)out)[i] = p;
}

// ---- embedding gather -> Xe[t*128+b][512] bf16 ----
__global__ void k_gather_emb(const float* __restrict__ emb, const int* __restrict__ tok,
                             unsigned short* __restrict__ Xe) {
  int i = blockIdx.x * 256 + threadIdx.x;  // 4096*512/4 = 524288
  int r = i >> 7, k4 = (i & 127) * 4;
  int b = r & 127, t = r >> 7;
  int tk = tok[b * 32 + t];
  float4 v = *(const float4*)(emb + (size_t)tk * 512 + k4);
  ushort4 p; p.x = f2bf(v.x); p.y = f2bf(v.y); p.z = f2bf(v.z); p.w = f2bf(v.w);
  ((ushort4*)Xe)[i] = p;
}

// ---- init h/c state from current_hidden_state (2,128,1024) ----
__global__ void k_init_state(const float* __restrict__ chs,
                             unsigned short* __restrict__ h0b1, unsigned short* __restrict__ h1b1,
                             float* __restrict__ h0f, float* __restrict__ c0f,
                             float* __restrict__ h1f, float* __restrict__ c1f) {
  int i = blockIdx.x * 256 + threadIdx.x;  // 65536
  int b = i >> 9, j = i & 511;
  float h0 = chs[b * 1024 + j], c0 = chs[b * 1024 + 512 + j];
  float h1 = chs[131072 + b * 1024 + j], c1 = chs[131072 + b * 1024 + 512 + j];
  h0f[i] = h0; c0f[i] = c0; h1f[i] = h1; c1f[i] = c1;
  h0b1[i] = f2bf(h0); h1b1[i] = f2bf(h1);
}

// ---- generic 128x128-tile GEMM: C[M][N] = A[M][K] * Bt[N][K]^T (+epilogue) ----
// MODE 0: proc  = leaky(acc + bias) -> outB (bf16)
// MODE 1: Cf    = acc + bias        -> outF
// MODE 2: Zx    = acc + add128[m&127][n] -> outF
template <int MODE>
__global__ __launch_bounds__(256, 2)
void k_gemm(const unsigned short* __restrict__ A, const unsigned short* __restrict__ Bt,
            const float* __restrict__ bias, const float* __restrict__ add128,
            float* __restrict__ outF, unsigned short* __restrict__ outB,
            int M, int N, int K) {
  __shared__ unsigned short As[4096];  // 128 x 32
  __shared__ unsigned short Bs[4096];
  int tid = threadIdx.x;
  int wave = tid >> 6, lane = tid & 63;
  int lr = lane & 15, lq = lane >> 4;
  int wm = (wave >> 1) * 64, wn = (wave & 1) * 64;
  int m0 = blockIdx.y * 128, n0 = blockIdx.x * 128;

  f4v acc[4][4];
  f4v zero = {0.0f, 0.0f, 0.0f, 0.0f};
#pragma unroll
  for (int i = 0; i < 4; i++)
#pragma unroll
    for (int j = 0; j < 4; j++) acc[i][j] = zero;

  int srow = tid >> 2, sofs = (tid & 3) * 8;
  int ar0 = m0 + srow, ar1 = ar0 + 64;
  int br0 = n0 + srow, br1 = br0 + 64;
  if (br0 >= N) br0 = N - 1;
  if (br1 >= N) br1 = N - 1;
  const unsigned short* Ag0 = A + (size_t)ar0 * K + sofs;
  const unsigned short* Ag1 = A + (size_t)ar1 * K + sofs;
  const unsigned short* Bg0 = Bt + (size_t)br0 * K + sofs;
  const unsigned short* Bg1 = Bt + (size_t)br1 * K + sofs;
  unsigned short* lA0 = &As[tid * 8];
  unsigned short* lA1 = &As[2048 + tid * 8];
  unsigned short* lB0 = &Bs[tid * 8];
  unsigned short* lB1 = &Bs[2048 + tid * 8];

  for (int k0 = 0; k0 < K; k0 += 32) {
    glds16(Ag0 + k0, lA0);
    glds16(Ag1 + k0, lA1);
    glds16(Bg0 + k0, lB0);
    glds16(Bg1 + k0, lB1);
    __syncthreads();
    s8v af[4], bfr[4];
#pragma unroll
    for (int i = 0; i < 4; i++) af[i] = *(const s8v*)&As[(wm + i * 16 + lr) * 32 + lq * 8];
#pragma unroll
    for (int i = 0; i < 4; i++) bfr[i] = *(const s8v*)&Bs[(wn + i * 16 + lr) * 32 + lq * 8];
#pragma unroll
    for (int i = 0; i < 4; i++)
#pragma unroll
      for (int j = 0; j < 4; j++)
        acc[i][j] = __builtin_amdgcn_mfma_f32_16x16x32_bf16(af[i], bfr[j], acc[i][j], 0, 0, 0);
    __syncthreads();
  }

#pragma unroll
  for (int i = 0; i < 4; i++) {
#pragma unroll
    for (int j = 0; j < 4; j++) {
      int nn = n0 + wn + j * 16 + lr;
      if (nn >= N) continue;
#pragma unroll
      for (int r = 0; r < 4; r++) {
        int mm = m0 + wm + i * 16 + lq * 4 + r;
        float v = acc[i][j][r];
        if (MODE == 0) {
          v += bias[nn];
          v = v > 0.0f ? v : 0.01f * v;
          outB[(size_t)mm * N + nn] = f2bf(v);
        } else if (MODE == 1) {
          v += bias[nn];
          outF[(size_t)mm * N + nn] = v;
        } else {
          v += add128[(size_t)(mm & 127) * N + nn];
          outF[(size_t)mm * N + nn] = v;
        }
      }
    }
  }
}

// ---- fused recurrence + incremental logits ----
// Blocks [0, nPB): phase jobs (4 wave-jobs per 256-thread block, 512 total):
//   stepB(tB): z1=[h0n|h1]@W1+b1 -> h1n,c1n (+H1all)
//   stepA(tA): z0=Zx[tA]+h0@W0h  -> h0n,c0n
// Blocks [nPB, nPB+79): logits tile for step tL (reads H1all written by the
//   PREVIOUS launch's stepB) -> out[(b*32+tL)*10000 + n].
__global__ __launch_bounds__(256, 2)
void k_phase_fused(const unsigned short* __restrict__ W0h_t, const unsigned short* __restrict__ W1_t,
                   const float* __restrict__ Zx, const float* __restrict__ b1,
                   unsigned short* __restrict__ h0b0, unsigned short* __restrict__ h0b1,
                   unsigned short* __restrict__ h1b0, unsigned short* __restrict__ h1b1,
                   float* __restrict__ h0f, float* __restrict__ c0f,
                   float* __restrict__ h1f, float* __restrict__ c1f,
                   unsigned short* __restrict__ H1all,
                   const unsigned short* __restrict__ Wout_t, const float* __restrict__ b_out,
                   float* __restrict__ out,
                   int tB, int doB, int tA, int doA, int tL, int doL, int nPB) {
  __shared__ unsigned short As[4096];
  __shared__ unsigned short Bs[4096];
  int tid = threadIdx.x;
  int wave = tid >> 6, lane = tid & 63;
  int lr = lane & 15, lq = lane >> 4;
  f4v zero = {0.0f, 0.0f, 0.0f, 0.0f};

  if ((int)blockIdx.x >= nPB) {
    // ---------------- logits tile: 128 rows (all b, t=tL) x 128 cols ----------------
    if (!doL) return;
    int lb = (int)blockIdx.x - nPB;           // 0..78
    int n0 = lb * 128;                        // N = 10000 ragged
    const unsigned short* A = H1all + (size_t)tL * 128 * 512;
    int wm = (wave >> 1) * 64, wn = (wave & 1) * 64;

    f4v acc[4][4];
#pragma unroll
    for (int i = 0; i < 4; i++)
#pragma unroll
      for (int j = 0; j < 4; j++) acc[i][j] = zero;

    int srow = tid >> 2, sofs = (tid & 3) * 8;
    int ar0 = srow, ar1 = srow + 64;          // M = 128 exactly
    int br0 = n0 + srow, br1 = n0 + srow + 64;
    if (br0 > 9999) br0 = 9999;               // ragged-N clamp; masked in epilogue
    if (br1 > 9999) br1 = 9999;
    const unsigned short* Ag0 = A + (size_t)ar0 * 512 + sofs;
    const unsigned short* Ag1 = A + (size_t)ar1 * 512 + sofs;
    const unsigned short* Bg0 = Wout_t + (size_t)br0 * 512 + sofs;
    const unsigned short* Bg1 = Wout_t + (size_t)br1 * 512 + sofs;
    unsigned short* lA0 = &As[tid * 8];
    unsigned short* lA1 = &As[2048 + tid * 8];
    unsigned short* lB0 = &Bs[tid * 8];
    unsigned short* lB1 = &Bs[2048 + tid * 8];

    for (int k0 = 0; k0 < 512; k0 += 32) {
      glds16(Ag0 + k0, lA0);
      glds16(Ag1 + k0, lA1);
      glds16(Bg0 + k0, lB0);
      glds16(Bg1 + k0, lB1);
      __syncthreads();
      s8v af[4], bfr[4];
#pragma unroll
      for (int i = 0; i < 4; i++) af[i] = *(const s8v*)&As[(wm + i * 16 + lr) * 32 + lq * 8];
#pragma unroll
      for (int i = 0; i < 4; i++) bfr[i] = *(const s8v*)&Bs[(wn + i * 16 + lr) * 32 + lq * 8];
#pragma unroll
      for (int i = 0; i < 4; i++)
#pragma unroll
        for (int j = 0; j < 4; j++)
          acc[i][j] = __builtin_amdgcn_mfma_f32_16x16x32_bf16(af[i], bfr[j], acc[i][j], 0, 0, 0);
      __syncthreads();
    }

#pragma unroll
    for (int i = 0; i < 4; i++) {
#pragma unroll
      for (int j = 0; j < 4; j++) {
        int nn = n0 + wn + j * 16 + lr;
        if (nn >= 10000) continue;
#pragma unroll
        for (int r = 0; r < 4; r++) {
          int b = wm + i * 16 + lq * 4 + r;   // row within 128 = batch index
          out[(size_t)(b * 32 + tL) * 10000 + nn] = acc[i][j][r] + b_out[nn];
        }
      }
    }
    return;
  }

  // ---------------- phase jobs: 4 wave-jobs per block ----------------
  int gid = (int)blockIdx.x * 4 + wave;       // 512 wave-jobs
  bool isB = gid < 256;
  if (isB && !doB) return;
  if (!isB && !doA) return;
  int id = gid & 255;
  int mt = id >> 5, jt = id & 31;             // 8 m-tiles x 32 j-tiles
  int m = mt * 16 + lr;                       // A-operand row = lane&15
  f4v acc[4] = {zero, zero, zero, zero};

  if (isB) {
    const unsigned short* h0r = (tB & 1) ? h0b1 : h0b0;   // h0buf[tB&1]
    const unsigned short* h1r = (tB & 1) ? h1b0 : h1b1;   // h1buf[(tB+1)&1]
    unsigned short* h1w = (tB & 1) ? h1b1 : h1b0;         // h1buf[tB&1]
    for (int kc = 0; kc < 32; kc++) {
      int kk = kc * 32 + lq * 8;
      const unsigned short* ap = (kk < 512) ? (h0r + m * 512 + kk)
                                            : (h1r + m * 512 + kk - 512);
      s8v a = *(const s8v*)ap;
#pragma unroll
      for (int g = 0; g < 4; g++) {
        int n = g * 512 + jt * 16 + lr;
        s8v b = *(const s8v*)(W1_t + (size_t)n * 1024 + kc * 32 + lq * 8);
        acc[g] = __builtin_amdgcn_mfma_f32_16x16x32_bf16(a, b, acc[g], 0, 0, 0);
      }
    }
    int j = jt * 16 + lr;
    float bi = b1[j], bo = b1[512 + j], bff = b1[1024 + j], bc = b1[1536 + j];
#pragma unroll
    for (int r = 0; r < 4; r++) {
      int mm = mt * 16 + lq * 4 + r;
      int idx = mm * 512 + j;
      float cprev = c1f[idx];
      float iv = sigm(acc[0][r] + bi);
      float ov = sigm(acc[1][r] + bo);
      float fv = sigm(acc[2][r] + bff);
      float cv = tanh_(acc[3][r] + bc);
      float cn = fv * cprev + iv * cv;
      float hn = ov * tanh_(cn);
      c1f[idx] = cn; h1f[idx] = hn;
      unsigned short hb = f2bf(hn);
      h1w[idx] = hb;
      H1all[(size_t)(tB * 128 + mm) * 512 + j] = hb;
    }
  } else {
    const unsigned short* h0r = (tA & 1) ? h0b0 : h0b1;   // h0buf[(tA+1)&1]
    unsigned short* h0w = (tA & 1) ? h0b1 : h0b0;         // h0buf[tA&1]
    for (int kc = 0; kc < 16; kc++) {
      s8v a = *(const s8v*)(h0r + m * 512 + kc * 32 + lq * 8);
#pragma unroll
      for (int g = 0; g < 4; g++) {
        int n = g * 512 + jt * 16 + lr;
        s8v b = *(const s8v*)(W0h_t + (size_t)n * 512 + kc * 32 + lq * 8);
        acc[g] = __builtin_amdgcn_mfma_f32_16x16x32_bf16(a, b, acc[g], 0, 0, 0);
      }
    }
    int j = jt * 16 + lr;
    const float* zrow = Zx + (size_t)tA * 128 * 2048;
#pragma unroll
    for (int r = 0; r < 4; r++) {
      int mm = mt * 16 + lq * 4 + r;
      int idx = mm * 512 + j;
      float cprev = c0f[idx];
      float iv = sigm(acc[0][r] + zrow[mm * 2048 + j]);
      float ov = sigm(acc[1][r] + zrow[mm * 2048 + 512 + j]);
      float fv = sigm(acc[2][r] + zrow[mm * 2048 + 1024 + j]);
      float cv = tanh_(acc[3][r] + zrow[mm * 2048 + 1536 + j]);
      float cn = fv * cprev + iv * cv;
      float hn = ov * tanh_(cn);
      c0f[idx] = cn; h0f[idx] = hn;
      h0w[idx] = f2bf(hn);
    }
  }
}

// ---- final hidden writeout: out[40960000 + (l*128+b)*1024 + j] ----
__global__ void k_write_hidden(const float* __restrict__ h0f, const float* __restrict__ c0f,
                               const float* __restrict__ h1f, const float* __restrict__ c1f,
                               float* __restrict__ out) {
  int idx = blockIdx.x * 256 + threadIdx.x;  // 262144
  int l = idx >> 17, rem = idx & 131071, b = rem >> 10, j = rem & 1023;
  const float* hs = l ? h1f : h0f;
  const float* cs = l ? c1f : c0f;
  float v = (j < 512) ? hs[b * 512 + j] : cs[b * 512 + (j - 512)];
  out[40960000 + idx] = v;
}

extern "C" void kernel_launch(void* const* d_in, const int* in_sizes, int n_in,
                              void* d_out, int out_size, void* d_ws, size_t ws_size,
                              hipStream_t stream) {
  const float* cnn  = (const float*)d_in[0];
  const int*   tok  = (const int*)d_in[1];
  const float* chs  = (const float*)d_in[2];
  const float* emb  = (const float*)d_in[3];
  const float* W_in = (const float*)d_in[4];
  const float* b_in = (const float*)d_in[5];
  const float* W0   = (const float*)d_in[6];
  const float* b0   = (const float*)d_in[7];
  const float* W1   = (const float*)d_in[8];
  const float* b1   = (const float*)d_in[9];
  const float* W_out= (const float*)d_in[10];
  const float* b_out= (const float*)d_in[11];
  float* out = (float*)d_out;

  char* p = (char*)d_ws;
  auto alloc = [&](size_t bytes) { char* q = p; p += (bytes + 255) & ~(size_t)255; return q; };
  unsigned short* Win_t  = (unsigned short*)alloc((size_t)512 * 2048 * 2);
  unsigned short* W0e_t  = (unsigned short*)alloc((size_t)2048 * 512 * 2);
  unsigned short* W0m_t  = (unsigned short*)alloc((size_t)2048 * 512 * 2);
  unsigned short* W0h_t  = (unsigned short*)alloc((size_t)2048 * 512 * 2);
  unsigned short* W1_t   = (unsigned short*)alloc((size_t)2048 * 1024 * 2);
  unsigned short* Wout_t = (unsigned short*)alloc((size_t)10000 * 512 * 2);
  unsigned short* cnn_b  = (unsigned short*)alloc((size_t)128 * 2048 * 2);
  unsigned short* proc_b = (unsigned short*)alloc((size_t)128 * 512 * 2);
  float*          Cf     = (float*)alloc((size_t)128 * 2048 * 4);
  unsigned short* Xe     = (unsigned short*)alloc((size_t)4096 * 512 * 2);
  float*          Zx     = (float*)alloc((size_t)4096 * 2048 * 4);
  unsigned short* h0b0   = (unsigned short*)alloc(65536 * 2);
  unsigned short* h0b1   = (unsigned short*)alloc(65536 * 2);
  unsigned short* h1b0   = (unsigned short*)alloc(65536 * 2);
  unsigned short* h1b1   = (unsigned short*)alloc(65536 * 2);
  float*          h0f    = (float*)alloc(65536 * 4);
  float*          c0f    = (float*)alloc(65536 * 4);
  float*          h1f    = (float*)alloc(65536 * 4);
  float*          c1f    = (float*)alloc(65536 * 4);
  unsigned short* H1all  = (unsigned short*)alloc((size_t)4096 * 512 * 2);
  // total ws use ~= 68 MB

  dim3 tb(32, 8);
  k_transpose_cvt<<<dim3(16, 64),  tb, 0, stream>>>(W_in, Win_t, 2048, 512);
  k_transpose_cvt<<<dim3(64, 16),  tb, 0, stream>>>(W0,               W0e_t, 512, 2048);
  k_transpose_cvt<<<dim3(64, 16),  tb, 0, stream>>>(W0 + 512 * 2048,  W0m_t, 512, 2048);
  k_transpose_cvt<<<dim3(64, 16),  tb, 0, stream>>>(W0 + 1024 * 2048, W0h_t, 512, 2048);
  k_transpose_cvt<<<dim3(64, 32),  tb, 0, stream>>>(W1, W1_t, 1024, 2048);
  k_transpose_cvt<<<dim3(313, 16), tb, 0, stream>>>(W_out, Wout_t, 512, 10000);
  k_cvt_bf16<<<256, 256, 0, stream>>>(cnn, cnn_b, 65536);

  // proc = leaky(cnn @ W_in + b_in)  (bf16 out)
  k_gemm<0><<<dim3(4, 1), 256, 0, stream>>>(cnn_b, Win_t, b_in, nullptr, nullptr, proc_b,
                                            128, 512, 2048);
  // Cf = proc @ W0[512:1024] + b0  (fp32, per-batch broadcast term of Zx)
  k_gemm<1><<<dim3(16, 1), 256, 0, stream>>>(proc_b, W0m_t, b0, nullptr, Cf, nullptr,
                                             128, 2048, 512);
  k_gather_emb<<<2048, 256, 0, stream>>>(emb, tok, Xe);
  // Zx[t*128+b] = emb_t @ W0[0:512] + Cf[b]
  k_gemm<2><<<dim3(16, 32), 256, 0, stream>>>(Xe, W0e_t, nullptr, Cf, Zx, nullptr,
                                              4096, 2048, 512);
  k_init_state<<<256, 256, 0, stream>>>(chs, h0b1, h1b1, h0f, c0f, h1f, c1f);

  // recurrence with fused incremental logits:
  //   launch 0:        stepA(0)
  //   launch t+1:      stepB(t) || stepA(t+1) || logits(t-1)   [t=0..31]
  //   final launch:    logits(31)
  const int NPB = 128;  // 128 phase blocks x 4 wave-jobs = 512 jobs
  k_phase_fused<<<NPB, 256, 0, stream>>>(W0h_t, W1_t, Zx, b1, h0b0, h0b1, h1b0, h1b1,
                                         h0f, c0f, h1f, c1f, H1all,
                                         Wout_t, b_out, out,
                                         0, 0, 0, 1, 0, 0, NPB);
  for (int t = 0; t < 32; t++) {
    int doL = (t >= 1) ? 1 : 0;               // logits(t-1): H1(t-1) done last launch
    int grid = NPB + (doL ? 79 : 0);
    k_phase_fused<<<grid, 256, 0, stream>>>(W0h_t, W1_t, Zx, b1, h0b0, h0b1, h1b0, h1b1,
                                            h0f, c0f, h1f, c1f, H1all,
                                            Wout_t, b_out, out,
                                            t, 1, t + 1, (t < 31) ? 1 : 0,
                                            t - 1, doL, NPB);
  }
  k_phase_fused<<<79, 256, 0, stream>>>(W0h_t, W1_t, Zx, b1, h0b0, h0b1, h1b0, h1b1,
                                        h0f, c0f, h1f, c1f, H1all,
                                        Wout_t, b_out, out,
                                        0, 0, 0, 0, 31, 1, 0);

  k_write_hidden<<<1024, 256, 0, stream>>>(h0f, c0f, h1f, c1f, out);
}

// Round 2
// 795.851 us; speedup vs baseline: 1.3265x; 1.3265x over previous
//
#include <hip/hip_runtime.h>

// ImageCaptionModel: B=128 T=32 V=10000 H=512 E=512 F=2048 NM=512
// D0=1536 D1=1024. All GEMMs bf16-MFMA (16x16x32) with fp32 accum.
// Round 2: round-0 structure (phase = 256 blocks x 128 thr, standalone logits
// GEMM) + depth-8 software-pipelined prefetch in the phase inner loops.
// The phase waves are latency-bound (0.5 waves/SIMD, L3-hit loads ~500cy);
// 40 outstanding loads/wave hide that latency.

typedef short s8v __attribute__((ext_vector_type(8)));   // 8 x bf16 bits
typedef float f4v __attribute__((ext_vector_type(4)));   // MFMA acc

__device__ __forceinline__ unsigned short f2bf(float f) {
  unsigned u = __float_as_uint(f);
  u += 0x7fffu + ((u >> 16) & 1u);          // round-to-nearest-even
  return (unsigned short)(u >> 16);
}
__device__ __forceinline__ float sigm(float x) { return 1.0f / (1.0f + __expf(-x)); }
__device__ __forceinline__ float tanh_(float x) { return 1.0f - 2.0f / (1.0f + __expf(2.0f * x)); }

__device__ __forceinline__ void glds16(const unsigned short* g, unsigned short* l) {
  __builtin_amdgcn_global_load_lds((const __attribute__((address_space(1))) void*)g,
                                   (__attribute__((address_space(3))) void*)l, 16, 0, 0);
}

// ---- transpose + fp32->bf16: dst[c][r] = src[r][c] ----
__global__ void k_transpose_cvt(const float* __restrict__ src, unsigned short* __restrict__ dst,
                                int R, int C) {
  __shared__ float tile[32][33];
  int c0 = blockIdx.x * 32, r0 = blockIdx.y * 32;
  int tx = threadIdx.x, ty = threadIdx.y;
#pragma unroll
  for (int i = 0; i < 4; i++) {
    int r = r0 + ty + i * 8, c = c0 + tx;
    if (r < R && c < C) tile[ty + i * 8][tx] = src[(size_t)r * C + c];
  }
  __syncthreads();
#pragma unroll
  for (int i = 0; i < 4; i++) {
    int c = c0 + ty + i * 8, r = r0 + tx;
    if (r < R && c < C) dst[(size_t)c * R + r] = f2bf(tile[tx][ty + i * 8]);
  }
}

// ---- fp32 -> bf16 (vec4) ----
__global__ void k_cvt_bf16(const float* __restrict__ in, unsigned short* __restrict__ out, int n4) {
  int i = blockIdx.x * 256 + threadIdx.x;
  if (i >= n4) return;
  float4 v = ((const float4*)in)[i];
  ushort4 p; p.x = f2bf(v.x); p.y = f2bf(v.y); p.z = f2bf(v.z); p.w = f2bf(v.w);
  ((ushort4*)out)[i] = p;
}

// ---- embedding gather -> Xe[t*128+b][512] bf16 ----
__global__ void k_gather_emb(const float* __restrict__ emb, const int* __restrict__ tok,
                             unsigned short* __restrict__ Xe) {
  int i = blockIdx.x * 256 + threadIdx.x;  // 4096*512/4 = 524288
  int r = i >> 7, k4 = (i & 127) * 4;
  int b = r & 127, t = r >> 7;
  int tk = tok[b * 32 + t];
  float4 v = *(const float4*)(emb + (size_t)tk * 512 + k4);
  ushort4 p; p.x = f2bf(v.x); p.y = f2bf(v.y); p.z = f2bf(v.z); p.w = f2bf(v.w);
  ((ushort4*)Xe)[i] = p;
}

// ---- init h/c state from current_hidden_state (2,128,1024) ----
__global__ void k_init_state(const float* __restrict__ chs,
                             unsigned short* __restrict__ h0b1, unsigned short* __restrict__ h1b1,
                             float* __restrict__ h0f, float* __restrict__ c0f,
                             float* __restrict__ h1f, float* __restrict__ c1f) {
  int i = blockIdx.x * 256 + threadIdx.x;  // 65536
  int b = i >> 9, j = i & 511;
  float h0 = chs[b * 1024 + j], c0 = chs[b * 1024 + 512 + j];
  float h1 = chs[131072 + b * 1024 + j], c1 = chs[131072 + b * 1024 + 512 + j];
  h0f[i] = h0; c0f[i] = c0; h1f[i] = h1; c1f[i] = c1;
  h0b1[i] = f2bf(h0); h1b1[i] = f2bf(h1);
}

// ---- generic 128x128-tile GEMM: C[M][N] = A[M][K] * Bt[N][K]^T (+epilogue) ----
// MODE 0: proc  = leaky(acc + bias) -> outB (bf16)
// MODE 1: Cf    = acc + bias        -> outF
// MODE 2: Zx    = acc + add128[m&127][n] -> outF
// MODE 3: logit = acc + bias -> out[(b*32+t)*N + n], b=m&127, t=m>>7 (N ragged)
template <int MODE>
__global__ __launch_bounds__(256, 2)
void k_gemm(const unsigned short* __restrict__ A, const unsigned short* __restrict__ Bt,
            const float* __restrict__ bias, const float* __restrict__ add128,
            float* __restrict__ outF, unsigned short* __restrict__ outB,
            int M, int N, int K) {
  __shared__ unsigned short As[4096];  // 128 x 32
  __shared__ unsigned short Bs[4096];
  int tid = threadIdx.x;
  int wave = tid >> 6, lane = tid & 63;
  int lr = lane & 15, lq = lane >> 4;
  int wm = (wave >> 1) * 64, wn = (wave & 1) * 64;
  int m0 = blockIdx.y * 128, n0 = blockIdx.x * 128;

  f4v acc[4][4];
  f4v zero = {0.0f, 0.0f, 0.0f, 0.0f};
#pragma unroll
  for (int i = 0; i < 4; i++)
#pragma unroll
    for (int j = 0; j < 4; j++) acc[i][j] = zero;

  int srow = tid >> 2, sofs = (tid & 3) * 8;
  int ar0 = m0 + srow, ar1 = ar0 + 64;
  int br0 = n0 + srow, br1 = br0 + 64;
  if (br0 >= N) br0 = N - 1;   // ragged-N clamp (logits); masked in epilogue
  if (br1 >= N) br1 = N - 1;
  const unsigned short* Ag0 = A + (size_t)ar0 * K + sofs;
  const unsigned short* Ag1 = A + (size_t)ar1 * K + sofs;
  const unsigned short* Bg0 = Bt + (size_t)br0 * K + sofs;
  const unsigned short* Bg1 = Bt + (size_t)br1 * K + sofs;
  unsigned short* lA0 = &As[tid * 8];
  unsigned short* lA1 = &As[2048 + tid * 8];
  unsigned short* lB0 = &Bs[tid * 8];
  unsigned short* lB1 = &Bs[2048 + tid * 8];

  for (int k0 = 0; k0 < K; k0 += 32) {
    glds16(Ag0 + k0, lA0);
    glds16(Ag1 + k0, lA1);
    glds16(Bg0 + k0, lB0);
    glds16(Bg1 + k0, lB1);
    __syncthreads();
    s8v af[4], bfr[4];
#pragma unroll
    for (int i = 0; i < 4; i++) af[i] = *(const s8v*)&As[(wm + i * 16 + lr) * 32 + lq * 8];
#pragma unroll
    for (int i = 0; i < 4; i++) bfr[i] = *(const s8v*)&Bs[(wn + i * 16 + lr) * 32 + lq * 8];
#pragma unroll
    for (int i = 0; i < 4; i++)
#pragma unroll
      for (int j = 0; j < 4; j++)
        acc[i][j] = __builtin_amdgcn_mfma_f32_16x16x32_bf16(af[i], bfr[j], acc[i][j], 0, 0, 0);
    __syncthreads();
  }

#pragma unroll
  for (int i = 0; i < 4; i++) {
#pragma unroll
    for (int j = 0; j < 4; j++) {
      int nn = n0 + wn + j * 16 + lr;       // C/D: col = lane&15
      if (nn >= N) continue;
#pragma unroll
      for (int r = 0; r < 4; r++) {
        int mm = m0 + wm + i * 16 + lq * 4 + r;  // C/D: row = (lane>>4)*4+reg
        float v = acc[i][j][r];
        if (MODE == 0) {
          v += bias[nn];
          v = v > 0.0f ? v : 0.01f * v;
          outB[(size_t)mm * N + nn] = f2bf(v);
        } else if (MODE == 1) {
          v += bias[nn];
          outF[(size_t)mm * N + nn] = v;
        } else if (MODE == 2) {
          v += add128[(size_t)(mm & 127) * N + nn];
          outF[(size_t)mm * N + nn] = v;
        } else {
          v += bias[nn];
          int b = mm & 127, t = mm >> 7;
          outF[(size_t)(b * 32 + t) * N + nn] = v;
        }
      }
    }
  }
}

// ---- fused recurrence phase: stepB(tB): z1=[h0n|h1]@W1+b1 -> h1n,c1n (+H1all)
//                              stepA(tA): z0=Zx[tA]+h0@W0h  -> h0n,c0n
// h0buf/h1buf are parity double-buffered bf16 GEMM inputs.
// Inner loops are depth-8 software-pipelined: 40 (stepB) / 16 (stepA) loads
// in flight per wave to hide ~500cy L3-hit latency at 0.5 waves/SIMD.
__global__ __launch_bounds__(128)
void k_phase(const unsigned short* __restrict__ W0h_t, const unsigned short* __restrict__ W1_t,
             const float* __restrict__ Zx, const float* __restrict__ b1,
             unsigned short* __restrict__ h0b0, unsigned short* __restrict__ h0b1,
             unsigned short* __restrict__ h1b0, unsigned short* __restrict__ h1b1,
             float* __restrict__ h0f, float* __restrict__ c0f,
             float* __restrict__ h1f, float* __restrict__ c1f,
             unsigned short* __restrict__ H1all,
             int tB, int doB, int tA, int doA) {
  int wave = threadIdx.x >> 6, lane = threadIdx.x & 63;
  int gid = blockIdx.x * 2 + wave;     // 512 wave-jobs
  bool isB = gid < 256;
  if (isB && !doB) return;
  if (!isB && !doA) return;
  int id = gid & 255;
  int mt = id >> 5, jt = id & 31;      // 8 m-tiles x 32 j-tiles
  int lr = lane & 15, lq = lane >> 4;
  int m = mt * 16 + lr;                // A-operand row = lane&15
  int lqo = lq * 8;
  f4v zero = {0.0f, 0.0f, 0.0f, 0.0f};
  f4v acc[4] = {zero, zero, zero, zero};

  if (isB) {
    const unsigned short* h0r = (tB & 1) ? h0b1 : h0b0;   // h0buf[tB&1]
    const unsigned short* h1r = (tB & 1) ? h1b0 : h1b1;   // h1buf[(tB+1)&1]
    unsigned short* h1w = (tB & 1) ? h1b1 : h1b0;         // h1buf[tB&1]

    const unsigned short* pA0 = h0r + m * 512 + lqo;        // K in [0,512)
    const unsigned short* pA1 = h1r + m * 512 + lqo - 512;  // K in [512,1024)
    const unsigned short* wb  = W1_t + (size_t)(jt * 16 + lr) * 1024 + lqo;

    s8v a_s[8];
    s8v b_s[8][4];
    auto issueB = [&](int kc, int slot) {
      int kcl = kc < 32 ? kc : 31;     // clamp: duplicate last-iter loads, unused
      int ko = kcl * 32;
      const unsigned short* ap = (ko + lqo < 512) ? (pA0 + ko) : (pA1 + ko);
      a_s[slot] = *(const s8v*)ap;
      b_s[slot][0] = *(const s8v*)(wb + ko);
      b_s[slot][1] = *(const s8v*)(wb + 524288 + ko);      // +512*1024
      b_s[slot][2] = *(const s8v*)(wb + 1048576 + ko);
      b_s[slot][3] = *(const s8v*)(wb + 1572864 + ko);
    };
#pragma unroll
    for (int s = 0; s < 8; s++) issueB(s, s);
#pragma unroll
    for (int kc = 0; kc < 32; kc++) {  // fully unrolled: slot indices static
      int slot = kc & 7;
      s8v a = a_s[slot];
      acc[0] = __builtin_amdgcn_mfma_f32_16x16x32_bf16(a, b_s[slot][0], acc[0], 0, 0, 0);
      acc[1] = __builtin_amdgcn_mfma_f32_16x16x32_bf16(a, b_s[slot][1], acc[1], 0, 0, 0);
      acc[2] = __builtin_amdgcn_mfma_f32_16x16x32_bf16(a, b_s[slot][2], acc[2], 0, 0, 0);
      acc[3] = __builtin_amdgcn_mfma_f32_16x16x32_bf16(a, b_s[slot][3], acc[3], 0, 0, 0);
      issueB(kc + 8, slot);
    }

    int j = jt * 16 + lr;
    float bi = b1[j], bo = b1[512 + j], bff = b1[1024 + j], bc = b1[1536 + j];
#pragma unroll
    for (int r = 0; r < 4; r++) {
      int mm = mt * 16 + lq * 4 + r;
      int idx = mm * 512 + j;
      float cprev = c1f[idx];
      float iv = sigm(acc[0][r] + bi);
      float ov = sigm(acc[1][r] + bo);
      float fv = sigm(acc[2][r] + bff);
      float cv = tanh_(acc[3][r] + bc);
      float cn = fv * cprev + iv * cv;
      float hn = ov * tanh_(cn);
      c1f[idx] = cn; h1f[idx] = hn;
      unsigned short hb = f2bf(hn);
      h1w[idx] = hb;
      H1all[(size_t)(tB * 128 + mm) * 512 + j] = hb;
    }
  } else {
    const unsigned short* h0r = (tA & 1) ? h0b0 : h0b1;   // h0buf[(tA+1)&1]
    unsigned short* h0w = (tA & 1) ? h0b1 : h0b0;         // h0buf[tA&1]

    const unsigned short* pA = h0r + m * 512 + lqo;
    const unsigned short* wb = W0h_t + (size_t)(jt * 16 + lr) * 512 + lqo;

    s8v a_s[8];
    s8v b_s[8][4];
    auto issueA = [&](int kc, int slot) {
      int kcl = kc < 16 ? kc : 15;
      int ko = kcl * 32;
      a_s[slot] = *(const s8v*)(pA + ko);
      b_s[slot][0] = *(const s8v*)(wb + ko);
      b_s[slot][1] = *(const s8v*)(wb + 262144 + ko);      // +512*512
      b_s[slot][2] = *(const s8v*)(wb + 524288 + ko);
      b_s[slot][3] = *(const s8v*)(wb + 786432 + ko);
    };
#pragma unroll
    for (int s = 0; s < 8; s++) issueA(s, s);
#pragma unroll
    for (int kc = 0; kc < 16; kc++) {  // fully unrolled: slot indices static
      int slot = kc & 7;
      s8v a = a_s[slot];
      acc[0] = __builtin_amdgcn_mfma_f32_16x16x32_bf16(a, b_s[slot][0], acc[0], 0, 0, 0);
      acc[1] = __builtin_amdgcn_mfma_f32_16x16x32_bf16(a, b_s[slot][1], acc[1], 0, 0, 0);
      acc[2] = __builtin_amdgcn_mfma_f32_16x16x32_bf16(a, b_s[slot][2], acc[2], 0, 0, 0);
      acc[3] = __builtin_amdgcn_mfma_f32_16x16x32_bf16(a, b_s[slot][3], acc[3], 0, 0, 0);
      issueA(kc + 8, slot);
    }

    int j = jt * 16 + lr;
    const float* zrow = Zx + (size_t)tA * 128 * 2048;
#pragma unroll
    for (int r = 0; r < 4; r++) {
      int mm = mt * 16 + lq * 4 + r;
      int idx = mm * 512 + j;
      float cprev = c0f[idx];
      float iv = sigm(acc[0][r] + zrow[mm * 2048 + j]);
      float ov = sigm(acc[1][r] + zrow[mm * 2048 + 512 + j]);
      float fv = sigm(acc[2][r] + zrow[mm * 2048 + 1024 + j]);
      float cv = tanh_(acc[3][r] + zrow[mm * 2048 + 1536 + j]);
      float cn = fv * cprev + iv * cv;
      float hn = ov * tanh_(cn);
      c0f[idx] = cn; h0f[idx] = hn;
      h0w[idx] = f2bf(hn);
    }
  }
}

// ---- final hidden writeout: out[40960000 + (l*128+b)*1024 + j] ----
__global__ void k_write_hidden(const float* __restrict__ h0f, const float* __restrict__ c0f,
                               const float* __restrict__ h1f, const float* __restrict__ c1f,
                               float* __restrict__ out) {
  int idx = blockIdx.x * 256 + threadIdx.x;  // 262144
  int l = idx >> 17, rem = idx & 131071, b = rem >> 10, j = rem & 1023;
  const float* hs = l ? h1f : h0f;
  const float* cs = l ? c1f : c0f;
  float v = (j < 512) ? hs[b * 512 + j] : cs[b * 512 + (j - 512)];
  out[40960000 + idx] = v;
}

extern "C" void kernel_launch(void* const* d_in, const int* in_sizes, int n_in,
                              void* d_out, int out_size, void* d_ws, size_t ws_size,
                              hipStream_t stream) {
  const float* cnn  = (const float*)d_in[0];
  const int*   tok  = (const int*)d_in[1];
  const float* chs  = (const float*)d_in[2];
  const float* emb  = (const float*)d_in[3];
  const float* W_in = (const float*)d_in[4];
  const float* b_in = (const float*)d_in[5];
  const float* W0   = (const float*)d_in[6];
  const float* b0   = (const float*)d_in[7];
  const float* W1   = (const float*)d_in[8];
  const float* b1   = (const float*)d_in[9];
  const float* W_out= (const float*)d_in[10];
  const float* b_out= (const float*)d_in[11];
  float* out = (float*)d_out;

  char* p = (char*)d_ws;
  auto alloc = [&](size_t bytes) { char* q = p; p += (bytes + 255) & ~(size_t)255; return q; };
  unsigned short* Win_t  = (unsigned short*)alloc((size_t)512 * 2048 * 2);
  unsigned short* W0e_t  = (unsigned short*)alloc((size_t)2048 * 512 * 2);
  unsigned short* W0m_t  = (unsigned short*)alloc((size_t)2048 * 512 * 2);
  unsigned short* W0h_t  = (unsigned short*)alloc((size_t)2048 * 512 * 2);
  unsigned short* W1_t   = (unsigned short*)alloc((size_t)2048 * 1024 * 2);
  unsigned short* Wout_t = (unsigned short*)alloc((size_t)10000 * 512 * 2);
  unsigned short* cnn_b  = (unsigned short*)alloc((size_t)128 * 2048 * 2);
  unsigned short* proc_b = (unsigned short*)alloc((size_t)128 * 512 * 2);
  float*          Cf     = (float*)alloc((size_t)128 * 2048 * 4);
  unsigned short* Xe     = (unsigned short*)alloc((size_t)4096 * 512 * 2);
  float*          Zx     = (float*)alloc((size_t)4096 * 2048 * 4);
  unsigned short* h0b0   = (unsigned short*)alloc(65536 * 2);
  unsigned short* h0b1   = (unsigned short*)alloc(65536 * 2);
  unsigned short* h1b0   = (unsigned short*)alloc(65536 * 2);
  unsigned short* h1b1   = (unsigned short*)alloc(65536 * 2);
  float*          h0f    = (float*)alloc(65536 * 4);
  float*          c0f    = (float*)alloc(65536 * 4);
  float*          h1f    = (float*)alloc(65536 * 4);
  float*          c1f    = (float*)alloc(65536 * 4);
  unsigned short* H1all  = (unsigned short*)alloc((size_t)4096 * 512 * 2);
  // total ws use ~= 68 MB

  dim3 tb(32, 8);
  k_transpose_cvt<<<dim3(16, 64),  tb, 0, stream>>>(W_in, Win_t, 2048, 512);
  k_transpose_cvt<<<dim3(64, 16),  tb, 0, stream>>>(W0,               W0e_t, 512, 2048);
  k_transpose_cvt<<<dim3(64, 16),  tb, 0, stream>>>(W0 + 512 * 2048,  W0m_t, 512, 2048);
  k_transpose_cvt<<<dim3(64, 16),  tb, 0, stream>>>(W0 + 1024 * 2048, W0h_t, 512, 2048);
  k_transpose_cvt<<<dim3(64, 32),  tb, 0, stream>>>(W1, W1_t, 1024, 2048);
  k_transpose_cvt<<<dim3(313, 16), tb, 0, stream>>>(W_out, Wout_t, 512, 10000);
  k_cvt_bf16<<<256, 256, 0, stream>>>(cnn, cnn_b, 65536);

  // proc = leaky(cnn @ W_in + b_in)  (bf16 out)
  k_gemm<0><<<dim3(4, 1), 256, 0, stream>>>(cnn_b, Win_t, b_in, nullptr, nullptr, proc_b,
                                            128, 512, 2048);
  // Cf = proc @ W0[512:1024] + b0  (fp32, per-batch broadcast term of Zx)
  k_gemm<1><<<dim3(16, 1), 256, 0, stream>>>(proc_b, W0m_t, b0, nullptr, Cf, nullptr,
                                             128, 2048, 512);
  k_gather_emb<<<2048, 256, 0, stream>>>(emb, tok, Xe);
  // Zx[t*128+b] = emb_t @ W0[0:512] + Cf[b]
  k_gemm<2><<<dim3(16, 32), 256, 0, stream>>>(Xe, W0e_t, nullptr, Cf, Zx, nullptr,
                                              4096, 2048, 512);
  k_init_state<<<256, 256, 0, stream>>>(chs, h0b1, h1b1, h0f, c0f, h1f, c1f);

  // recurrence: stepA(0), then [stepB(t) || stepA(t+1)] for t=0..31
  k_phase<<<256, 128, 0, stream>>>(W0h_t, W1_t, Zx, b1, h0b0, h0b1, h1b0, h1b1,
                                   h0f, c0f, h1f, c1f, H1all, 0, 0, 0, 1);
  for (int t = 0; t < 32; t++)
    k_phase<<<256, 128, 0, stream>>>(W0h_t, W1_t, Zx, b1, h0b0, h0b1, h1b0, h1b1,
                                     h0f, c0f, h1f, c1f, H1all, t, 1, t + 1, (t < 31) ? 1 : 0);

  // logits = H1all @ W_out + b_out  -> d_out[(b*32+t)*10000 + v]
  k_gemm<3><<<dim3(79, 32), 256, 0, stream>>>(H1all, Wout_t, b_out, nullptr, out, nullptr,
                                              4096, 10000, 512);
  k_write_hidden<<<1024, 256, 0, stream>>>(h0f, c0f, h1f, c1f, out);
}